// Round 1
// baseline (715.264 us; speedup 1.0000x reference)
//
#include <hip/hip_runtime.h>
#include <stdint.h>

#define TSEQ 2048
#define DMODEL 2048
#define NQKV 6144
#define NTOT 8192

static constexpr float LAM_INIT = 0.7008206670670481f;   // 0.8 - 0.6*exp(-1.8)
static constexpr float QK_SCALE = 0.08838834764831845f;  // 128^-0.5
static constexpr float NEG_BIG = -1e30f;

typedef float f32x4 __attribute__((ext_vector_type(4)));
typedef short s16x8 __attribute__((ext_vector_type(8)));

__device__ __forceinline__ unsigned short f2bf(float f) {
  unsigned u = __builtin_bit_cast(unsigned, f);
  u += 0x7fffu + ((u >> 16) & 1u);
  return (unsigned short)(u >> 16);
}
__device__ __forceinline__ float bf2f(unsigned short h) {
  unsigned u = ((unsigned)h) << 16;
  return __builtin_bit_cast(float, u);
}
__device__ __forceinline__ unsigned pk2(float a, float b) {
  return (unsigned)f2bf(a) | ((unsigned)f2bf(b) << 16);
}

// D = A*B + D, 16x16x32 bf16. Inline asm: guaranteed to assemble on gfx950
// (HK pattern); layouts: A row=l&15,k=(l>>4)*8+j ; B col=l&15,k=(l>>4)*8+j ;
// D col=l&15,row=(l>>4)*4+r  (m89/m92-verified).
__device__ __forceinline__ void mfma_bf16(f32x4& d, s16x8 a, s16x8 b) {
  asm("v_mfma_f32_16x16x32_bf16 %0, %1, %2, %0" : "+v"(d) : "v"(a), "v"(b));
}

__device__ __forceinline__ void gld_lds16(const void* g, void* l) {
  __builtin_amdgcn_global_load_lds(
      (const __attribute__((address_space(1))) unsigned int*)g,
      (__attribute__((address_space(3))) unsigned int*)l, 16, 0, 0);
}

// ---------------- prep: fp32 -> bf16 convert ----------------
__global__ void k_cvt(const float* __restrict__ in, unsigned short* __restrict__ o, int n) {
  const int i = (blockIdx.x * 256 + threadIdx.x) * 8;
  if (i >= n) return;
  float4 a = *(const float4*)(in + i);
  float4 b = *(const float4*)(in + i + 4);
  uint4 u;
  u.x = pk2(a.x, a.y); u.y = pk2(a.z, a.w);
  u.z = pk2(b.x, b.y); u.w = pk2(b.z, b.w);
  *(uint4*)(o + i) = u;
}

// ---------------- prep: rope tables ----------------
__global__ void k_rope(float* __restrict__ ct, float* __restrict__ st) {
  const int id = blockIdx.x * 256 + threadIdx.x;  // 2048*64
  const int t = id >> 6, j = id & 63;
  const float inv = powf(10000.f, -(float)j * (1.f / 64.f));
  const float f = (float)t * inv;
  ct[id] = cosf(f);
  st[id] = sinf(f);
}

// ---------------- prep: W [K][N] f32 -> Wt [N][K] bf16 ----------------
__global__ void k_trans(const float* __restrict__ W, unsigned short* __restrict__ wt,
                        int N, int rowoff) {
  __shared__ __align__(16) unsigned short tl[64][72];
  const int tid = threadIdx.x;
  const int n0 = blockIdx.x * 64, k0 = blockIdx.y * 64;
#pragma unroll
  for (int i = 0; i < 4; ++i) {
    const int idx = tid + i * 256;          // 1024 float4 slots = 64 rows x 16
    const int r = idx >> 4, c4 = idx & 15;
    float4 v = *(const float4*)(W + (size_t)(k0 + r) * N + n0 + c4 * 4);
    tl[c4 * 4 + 0][r] = f2bf(v.x);
    tl[c4 * 4 + 1][r] = f2bf(v.y);
    tl[c4 * 4 + 2][r] = f2bf(v.z);
    tl[c4 * 4 + 3][r] = f2bf(v.w);
  }
  __syncthreads();
#pragma unroll
  for (int i = 0; i < 2; ++i) {
    const int idx = tid + i * 256;          // 512 uint4 slots = 64 rows x 8
    const int rn = idx >> 3, c8 = idx & 7;
    uint4 vv = *(const uint4*)(&tl[rn][c8 * 8]);
    *(uint4*)(wt + (size_t)(rowoff + n0 + rn) * 2048 + k0 + c8 * 8) = vv;
  }
}

// ---------------- GEMM: C[4096][8192] = xb[4096][2048] @ Wt[8192][2048]^T ----
// m97 structure: 128x128 tile, BK=64, global_load_lds w=16, XOR-swizzled LDS.
// SiLU applied to gate columns (n >= 6144).
__global__ __launch_bounds__(256, 2) void k_gemm(
    const unsigned short* __restrict__ A, const unsigned short* __restrict__ B,
    unsigned short* __restrict__ C) {
  __shared__ __align__(16) unsigned short As[128 * 64];
  __shared__ __align__(16) unsigned short Bs[128 * 64];
  const int tid = threadIdx.x;
  const int l = tid & 63;
  const int ll = l & 15, lg = l >> 4;
  const int w = tid >> 6;
  const int wm = (w >> 1) * 64, wn = (w & 1) * 64;
  const int m0 = blockIdx.y * 128;
  const int n0 = blockIdx.x * 128;

  f32x4 acc[4][4];
#pragma unroll
  for (int i = 0; i < 4; ++i)
#pragma unroll
    for (int j = 0; j < 4; ++j) acc[i][j] = (f32x4){0.f, 0.f, 0.f, 0.f};

  for (int kt = 0; kt < 32; ++kt) {
    const int k0 = kt * 64;
    __syncthreads();
#pragma unroll
    for (int i = 0; i < 4; ++i) {
      const int s = tid + i * 256;
      const int row = s >> 3;
      const int col = ((s & 7) ^ (row & 7)) << 3;  // inverse-swizzled source
      gld_lds16(A + (size_t)(m0 + row) * 2048 + k0 + col, &As[s * 8]);
      gld_lds16(B + (size_t)(n0 + row) * 2048 + k0 + col, &Bs[s * 8]);
    }
    __syncthreads();
#pragma unroll
    for (int kc = 0; kc < 2; ++kc) {
      s16x8 af[4], bfv[4];
#pragma unroll
      for (int mf = 0; mf < 4; ++mf) {
        const int r = wm + mf * 16 + ll;
        af[mf] = *(const s16x8*)((const char*)As + r * 128 +
                                 ((kc * 64 + lg * 16) ^ ((r & 7) << 4)));
      }
#pragma unroll
      for (int nf = 0; nf < 4; ++nf) {
        const int r = wn + nf * 16 + ll;
        bfv[nf] = *(const s16x8*)((const char*)Bs + r * 128 +
                                  ((kc * 64 + lg * 16) ^ ((r & 7) << 4)));
      }
#pragma unroll
      for (int mf = 0; mf < 4; ++mf)
#pragma unroll
        for (int nf = 0; nf < 4; ++nf) mfma_bf16(acc[mf][nf], af[mf], bfv[nf]);
    }
  }
  const bool gate = (n0 >= NQKV);
#pragma unroll
  for (int mf = 0; mf < 4; ++mf)
#pragma unroll
    for (int nf = 0; nf < 4; ++nf)
#pragma unroll
      for (int r = 0; r < 4; ++r) {
        const int row = m0 + wm + mf * 16 + lg * 4 + r;
        const int col = n0 + wn + nf * 16 + ll;
        float v = acc[mf][nf][r];
        if (gate) v = v / (1.f + __expf(-v));  // silu
        C[(size_t)row * NTOT + col] = f2bf(v);
      }
}

// ---------------- postproc: rmsnorm+rope on q,k; transpose v ----------------
// grid (ttile32, H16, b2). 256 thr: 64 rows x 4 lanes.
__global__ void k_post(const unsigned short* __restrict__ cc,
                       const float* __restrict__ ctab, const float* __restrict__ stab,
                       unsigned short* __restrict__ qb, unsigned short* __restrict__ kb,
                       unsigned short* __restrict__ vtb) {
  __shared__ __align__(16) unsigned short lv[128][72];
  const int tid = threadIdx.x;
  const int t0 = blockIdx.x * 64;
  const int H = blockIdx.y;
  const int b = blockIdx.z;
  const int row = tid >> 2, c = tid & 3;
  const int t = t0 + row;
  const int sd = H & 1, sh = H >> 1;
  const size_t qkbase = ((((size_t)sd * 2 + b) * 8 + sh) * TSEQ) * 128;
  const size_t ccrow = (size_t)(b * TSEQ + t) * NTOT + (size_t)H * 384;

#pragma unroll
  for (int part = 0; part < 2; ++part) {
    const unsigned short* src = cc + ccrow + part * 128 + c * 32;
    float x[32];
#pragma unroll
    for (int j = 0; j < 4; ++j) {
      uint4 v = *(const uint4*)(src + j * 8);
      x[j * 8 + 0] = bf2f((unsigned short)(v.x & 0xffff));
      x[j * 8 + 1] = bf2f((unsigned short)(v.x >> 16));
      x[j * 8 + 2] = bf2f((unsigned short)(v.y & 0xffff));
      x[j * 8 + 3] = bf2f((unsigned short)(v.y >> 16));
      x[j * 8 + 4] = bf2f((unsigned short)(v.z & 0xffff));
      x[j * 8 + 5] = bf2f((unsigned short)(v.z >> 16));
      x[j * 8 + 6] = bf2f((unsigned short)(v.w & 0xffff));
      x[j * 8 + 7] = bf2f((unsigned short)(v.w >> 16));
    }
    float ssq = 0.f;
#pragma unroll
    for (int i = 0; i < 32; ++i) ssq += x[i] * x[i];
    ssq += __shfl_xor(ssq, 1);
    ssq += __shfl_xor(ssq, 2);
    const float rms = rsqrtf(ssq * (1.f / 128.f) + 1e-6f);
#pragma unroll
    for (int i = 0; i < 32; ++i) x[i] *= rms;
    float px[32];
#pragma unroll
    for (int i = 0; i < 32; ++i) px[i] = __shfl_xor(x[i], 2);
    const int jb = (c & 1) * 32;
    const float sgn = (c < 2) ? 1.f : -1.f;
    float ov[32];
#pragma unroll
    for (int i = 0; i < 32; ++i) {
      const float cs = ctab[t * 64 + jb + i];
      const float sn = stab[t * 64 + jb + i];
      ov[i] = x[i] * cs + sgn * px[i] * sn;  // c<2: x1*c+x2*s ; c>=2: -x1*s+x2*c
    }
    unsigned short* dst = (part == 0 ? qb : kb) + qkbase + (size_t)t * 128 + c * 32;
#pragma unroll
    for (int j = 0; j < 4; ++j) {
      uint4 u;
      u.x = pk2(ov[j * 8 + 0], ov[j * 8 + 1]);
      u.y = pk2(ov[j * 8 + 2], ov[j * 8 + 3]);
      u.z = pk2(ov[j * 8 + 4], ov[j * 8 + 5]);
      u.w = pk2(ov[j * 8 + 6], ov[j * 8 + 7]);
      *(uint4*)(dst + j * 8) = u;
    }
  }

  // v: transpose [64 t][128 dv] -> vtb[b][sh][dv][t]
  {
    const unsigned short* src = cc + ccrow + 256 + c * 32;
#pragma unroll
    for (int j = 0; j < 4; ++j) {
      uint4 v = *(const uint4*)(src + j * 8);
      const int base = c * 32 + j * 8;
      lv[base + 0][row] = (unsigned short)(v.x & 0xffff);
      lv[base + 1][row] = (unsigned short)(v.x >> 16);
      lv[base + 2][row] = (unsigned short)(v.y & 0xffff);
      lv[base + 3][row] = (unsigned short)(v.y >> 16);
      lv[base + 4][row] = (unsigned short)(v.z & 0xffff);
      lv[base + 5][row] = (unsigned short)(v.z >> 16);
      lv[base + 6][row] = (unsigned short)(v.w & 0xffff);
      lv[base + 7][row] = (unsigned short)(v.w >> 16);
    }
  }
  __syncthreads();
#pragma unroll
  for (int i = 0; i < 4; ++i) {
    const int sl = tid + i * 256;
    const int dv = sl >> 3, c8 = sl & 7;
    uint4 vv = *(const uint4*)(&lv[dv][c8 * 8]);
    const size_t off = (((size_t)b * 8 + sh) * 256 + sd * 128 + dv) * TSEQ + t0 + c8 * 8;
    *(uint4*)(vtb + off) = vv;
  }
}

// ---------------- attention staging ----------------
__device__ __forceinline__ void attn_stage(const unsigned short* kg, const unsigned short* vg,
                                           unsigned short* Kd, unsigned short* Vd, int tid) {
#pragma unroll
  for (int i = 0; i < 4; ++i) {  // K tile: 64 rows x 256B (16 slots)
    const int sl = tid + i * 256;
    const int row = sl >> 4;
    const int p = sl & 15;
    const int col = (((p & 8) | ((p & 7) ^ (row & 7)))) << 3;
    gld_lds16(kg + (size_t)row * 128 + col, Kd + sl * 8);
  }
#pragma unroll
  for (int i = 0; i < 8; ++i) {  // Vt tile: 256 rows x 128B (8 slots)
    const int sl = tid + i * 256;
    const int row = sl >> 3;
    const int col = ((sl & 7) ^ (row & 7)) << 3;
    gld_lds16(vg + (size_t)row * TSEQ + col, Vd + sl * 8);
  }
}

// ---------------- flash attention, one stream per block ----------------
// grid (qt16, sh8, b*2+s 4). QBLK=128, KBLK=64, 4 waves.
// S-phase: wave w owns q rows [w*32,+32). PV: wave owns (q half, dv half).
__global__ __launch_bounds__(256, 1) void k_attn(
    const unsigned short* __restrict__ qb, const unsigned short* __restrict__ kb,
    const unsigned short* __restrict__ vtb, unsigned short* __restrict__ ys) {
  __shared__ __align__(16) unsigned short Ks[2][64 * 128];
  __shared__ __align__(16) unsigned short Vts[2][256 * 64];
  __shared__ __align__(16) unsigned short Ps[128 * 72];  // pad->stride 144B (bank-safe)
  __shared__ float scs[128];
  __shared__ float lbuf[128];

  const int tid = threadIdx.x;
  const int l = tid & 63;
  const int ll = l & 15, lg = l >> 4;
  const int w = tid >> 6;
  const int qt = blockIdx.x;
  const int sh = blockIdx.y;
  const int b = blockIdx.z >> 1;
  const int s = blockIdx.z & 1;

  const size_t qkbase = ((((size_t)s * 2 + b) * 8 + sh) * TSEQ) * 128;
  const size_t vtbase = (((size_t)b * 8 + sh) * 256) * TSEQ;

  s16x8 qfr[2][4];
#pragma unroll
  for (int qf = 0; qf < 2; ++qf)
#pragma unroll
    for (int dc = 0; dc < 4; ++dc) {
      const int row = qt * 128 + w * 32 + qf * 16 + ll;
      qfr[qf][dc] = *(const s16x8*)(qb + qkbase + (size_t)row * 128 + dc * 32 + lg * 8);
    }

  float m_[2][4], ls_[2][4];
#pragma unroll
  for (int qf = 0; qf < 2; ++qf)
#pragma unroll
    for (int r = 0; r < 4; ++r) { m_[qf][r] = NEG_BIG; ls_[qf][r] = 0.f; }

  f32x4 acc[4][8];
#pragma unroll
  for (int i = 0; i < 4; ++i)
#pragma unroll
    for (int j = 0; j < 8; ++j) acc[i][j] = (f32x4){0.f, 0.f, 0.f, 0.f};

  const int qrow0 = (w >> 1) * 64;
  const int dv0 = (w & 1) * 128;
  const int nkt = 2 * qt + 2;

  attn_stage(kb + qkbase + (size_t)0 * 128, vtb + vtbase + 0, Ks[0], Vts[0], tid);
  __syncthreads();

  for (int kt = 0; kt < nkt; ++kt) {
    const int cur = kt & 1;
    if (kt + 1 < nkt)
      attn_stage(kb + qkbase + (size_t)((kt + 1) * 64) * 128, vtb + vtbase + (kt + 1) * 64,
                 Ks[cur ^ 1], Vts[cur ^ 1], tid);

    // ---- S phase: S = Q K^T for this wave's 32 rows ----
    f32x4 sacc[2][4];
#pragma unroll
    for (int qf = 0; qf < 2; ++qf)
#pragma unroll
      for (int kvf = 0; kvf < 4; ++kvf) sacc[qf][kvf] = (f32x4){0.f, 0.f, 0.f, 0.f};
#pragma unroll
    for (int dc = 0; dc < 4; ++dc) {
#pragma unroll
      for (int kvf = 0; kvf < 4; ++kvf) {
        const int r = kvf * 16 + ll;
        s16x8 kf = *(const s16x8*)((const char*)Ks[cur] + r * 256 +
                                   ((dc * 64 + lg * 16) ^ ((r & 7) << 4)));
        mfma_bf16(sacc[0][kvf], qfr[0][dc], kf);
        mfma_bf16(sacc[1][kvf], qfr[1][dc], kf);
      }
    }
    const bool mask = (kt >= 2 * qt);
#pragma unroll
    for (int qf = 0; qf < 2; ++qf) {
      float sv[4][4];
#pragma unroll
      for (int kvf = 0; kvf < 4; ++kvf)
#pragma unroll
        for (int r = 0; r < 4; ++r) {
          float xv = sacc[qf][kvf][r] * QK_SCALE;
          if (mask) {
            const int kvg = kt * 64 + kvf * 16 + ll;
            const int qg = qt * 128 + w * 32 + qf * 16 + lg * 4 + r;
            if (kvg > qg) xv = NEG_BIG;
          }
          sv[kvf][r] = xv;
        }
#pragma unroll
      for (int r = 0; r < 4; ++r) {
        float mx = fmaxf(fmaxf(sv[0][r], sv[1][r]), fmaxf(sv[2][r], sv[3][r]));
        mx = fmaxf(mx, __shfl_xor(mx, 1));
        mx = fmaxf(mx, __shfl_xor(mx, 2));
        mx = fmaxf(mx, __shfl_xor(mx, 4));
        mx = fmaxf(mx, __shfl_xor(mx, 8));
        const float mnew = fmaxf(m_[qf][r], mx);
        const float scr = __expf(m_[qf][r] - mnew);
        m_[qf][r] = mnew;
        float rs = 0.f;
#pragma unroll
        for (int kvf = 0; kvf < 4; ++kvf) {
          const float p = __expf(sv[kvf][r] - mnew);
          sv[kvf][r] = p;
          rs += p;
        }
        rs += __shfl_xor(rs, 1);
        rs += __shfl_xor(rs, 2);
        rs += __shfl_xor(rs, 4);
        rs += __shfl_xor(rs, 8);
        ls_[qf][r] = ls_[qf][r] * scr + rs;
        const int prow = w * 32 + qf * 16 + lg * 4 + r;
        if (ll == 0) scs[prow] = scr;
#pragma unroll
        for (int kvf = 0; kvf < 4; ++kvf)
          Ps[prow * 72 + kvf * 16 + ll] = f2bf(sv[kvf][r]);
      }
    }
    __syncthreads();

    // ---- PV phase: acc (64q x 128dv quadrant) += P * V ----
    float scv[4][4];
#pragma unroll
    for (int qf = 0; qf < 4; ++qf)
#pragma unroll
      for (int r = 0; r < 4; ++r) scv[qf][r] = scs[qrow0 + qf * 16 + lg * 4 + r];
#pragma unroll
    for (int qf = 0; qf < 4; ++qf)
#pragma unroll
      for (int dvf = 0; dvf < 8; ++dvf) {
        f32x4 t = acc[qf][dvf];
        t[0] *= scv[qf][0]; t[1] *= scv[qf][1]; t[2] *= scv[qf][2]; t[3] *= scv[qf][3];
        acc[qf][dvf] = t;
      }
#pragma unroll
    for (int kc = 0; kc < 2; ++kc) {
      s16x8 pa[4];
#pragma unroll
      for (int qf = 0; qf < 4; ++qf)
        pa[qf] = *(const s16x8*)((const char*)Ps + (qrow0 + qf * 16 + ll) * 144 +
                                 kc * 64 + lg * 16);
#pragma unroll
      for (int dvf = 0; dvf < 8; ++dvf) {
        const int r = dv0 + dvf * 16 + ll;
        s16x8 vb = *(const s16x8*)((const char*)Vts[cur] + r * 128 +
                                   ((kc * 64 + lg * 16) ^ ((r & 7) << 4)));
#pragma unroll
        for (int qf = 0; qf < 4; ++qf) mfma_bf16(acc[qf][dvf], pa[qf], vb);
      }
    }
    __syncthreads();
  }

  if (ll == 0) {
#pragma unroll
    for (int qf = 0; qf < 2; ++qf)
#pragma unroll
      for (int r = 0; r < 4; ++r) lbuf[w * 32 + qf * 16 + lg * 4 + r] = ls_[qf][r];
  }
  __syncthreads();
  const size_t ybase = ((((size_t)s * 2 + b) * 8 + sh) * TSEQ) * 256;
#pragma unroll
  for (int qf = 0; qf < 4; ++qf) {
    float li[4];
#pragma unroll
    for (int r = 0; r < 4; ++r) li[r] = 1.f / lbuf[qrow0 + qf * 16 + lg * 4 + r];
#pragma unroll
    for (int dvf = 0; dvf < 8; ++dvf)
#pragma unroll
      for (int r = 0; r < 4; ++r) {
        const int row = qt * 128 + qrow0 + qf * 16 + lg * 4 + r;
        const int col = dv0 + dvf * 16 + ll;
        ys[ybase + (size_t)row * 256 + col] = f2bf(acc[qf][dvf][r] * li[r]);
      }
  }
}

// ---------------- final: y = rmsnorm((y1 - lam*y2)*g) * (1-LAM_INIT) --------
__global__ void k_final(const unsigned short* __restrict__ ys,
                        const unsigned short* __restrict__ cc,
                        const float* __restrict__ lq1, const float* __restrict__ lk1,
                        const float* __restrict__ lq2, const float* __restrict__ lk2,
                        float* __restrict__ out) {
  const int tid = threadIdx.x;
  const int row = tid >> 2, c = tid & 3;
  const int t = blockIdx.x * 64 + row;
  const int sh = blockIdx.y;
  const int b = blockIdx.z;

  float d1 = 0.f, d2 = 0.f;
  for (int j = 0; j < 64; ++j) {
    d1 += lq1[sh * 64 + j] * lk1[sh * 64 + j];
    d2 += lq2[sh * 64 + j] * lk2[sh * 64 + j];
  }
  const float lam = __expf(d1) - __expf(d2) + LAM_INIT;

  const size_t y1o = ((((size_t)0 * 2 + b) * 8 + sh) * TSEQ + t) * 256 + c * 64;
  const size_t y2o = ((((size_t)1 * 2 + b) * 8 + sh) * TSEQ + t) * 256 + c * 64;
  const size_t go = (size_t)(b * TSEQ + t) * NTOT + NQKV + sh * 256 + c * 64;

  float y[64];
#define UNPK(r0, r1, aa, dd, gg)                                                   \
  r0 = (bf2f((unsigned short)((aa) & 0xffff)) - lam * bf2f((unsigned short)((dd) & 0xffff))) * \
       bf2f((unsigned short)((gg) & 0xffff));                                      \
  r1 = (bf2f((unsigned short)((aa) >> 16)) - lam * bf2f((unsigned short)((dd) >> 16))) *       \
       bf2f((unsigned short)((gg) >> 16));
#pragma unroll
  for (int j = 0; j < 8; ++j) {
    uint4 a = *(const uint4*)(ys + y1o + j * 8);
    uint4 d = *(const uint4*)(ys + y2o + j * 8);
    uint4 g = *(const uint4*)(cc + go + j * 8);
    UNPK(y[j * 8 + 0], y[j * 8 + 1], a.x, d.x, g.x)
    UNPK(y[j * 8 + 2], y[j * 8 + 3], a.y, d.y, g.y)
    UNPK(y[j * 8 + 4], y[j * 8 + 5], a.z, d.z, g.z)
    UNPK(y[j * 8 + 6], y[j * 8 + 7], a.w, d.w, g.w)
  }
#undef UNPK
  float ssq = 0.f;
#pragma unroll
  for (int i = 0; i < 64; ++i) ssq += y[i] * y[i];
  ssq += __shfl_xor(ssq, 1);
  ssq += __shfl_xor(ssq, 2);
  const float sc = rsqrtf(ssq * (1.f / 256.f) + 1e-6f) * (1.f - LAM_INIT);
  float* op = out + (size_t)(b * TSEQ + t) * DMODEL + sh * 256 + c * 64;
#pragma unroll
  for (int j = 0; j < 16; ++j) {
    float4 v = {y[j * 4] * sc, y[j * 4 + 1] * sc, y[j * 4 + 2] * sc, y[j * 4 + 3] * sc};
    *(float4*)(op + j * 4) = v;
  }
}

extern "C" void kernel_launch(void* const* d_in, const int* in_sizes, int n_in,
                              void* d_out, int out_size, void* d_ws, size_t ws_size,
                              hipStream_t stream) {
  (void)in_sizes; (void)n_in; (void)out_size; (void)ws_size;
  const float* x = (const float*)d_in[0];
  const float* wqkv = (const float*)d_in[1];
  const float* lq1 = (const float*)d_in[2];
  const float* lk1 = (const float*)d_in[3];
  const float* lq2 = (const float*)d_in[4];
  const float* lk2 = (const float*)d_in[5];
  const float* wg = (const float*)d_in[6];
  float* out = (float*)d_out;
  char* ws = (char*)d_ws;

  // Workspace layout (peak 152,043,520 B):
  //   [0, 16.8M)   xb   (x bf16)                -- dead after GEMM
  //   [16.8M,50.3M) wt  (W^T bf16, qkv|g rows)  -- dead after GEMM
  //   [50.3M,117.4M) cc (GEMM out bf16, silu'd gate cols)
  //   [117.4M,151.0M) ys (attn out bf16, both streams)
  //   [151.0M,152.0M) rope tables
  //   qbf/kbf/vtb alias [0,50.3M) after GEMM.
  unsigned short* xb = (unsigned short*)(ws);
  unsigned short* wt = (unsigned short*)(ws + (size_t)16777216);
  unsigned short* cc = (unsigned short*)(ws + (size_t)50331648);
  unsigned short* ysb = (unsigned short*)(ws + (size_t)117440512);
  float* ctab = (float*)(ws + (size_t)150994944);
  float* stab = (float*)(ws + (size_t)151519232);
  unsigned short* qbf = (unsigned short*)(ws);
  unsigned short* kbf = (unsigned short*)(ws + (size_t)16777216);
  unsigned short* vtb = (unsigned short*)(ws + (size_t)33554432);

  hipLaunchKernelGGL(k_cvt, dim3(4096), dim3(256), 0, stream, x, xb, 8388608);
  hipLaunchKernelGGL(k_rope, dim3(512), dim3(256), 0, stream, ctab, stab);
  hipLaunchKernelGGL(k_trans, dim3(96, 32), dim3(256), 0, stream, wqkv, wt, 6144, 0);
  hipLaunchKernelGGL(k_trans, dim3(32, 32), dim3(256), 0, stream, wg, wt, 2048, 6144);
  hipLaunchKernelGGL(k_gemm, dim3(64, 32), dim3(256), 0, stream, xb, wt, cc);
  hipLaunchKernelGGL(k_post, dim3(32, 16, 2), dim3(256), 0, stream, cc, ctab, stab, qbf, kbf, vtb);
  hipLaunchKernelGGL(k_attn, dim3(16, 8, 4), dim3(256), 0, stream, qbf, kbf, vtb, ysb);
  hipLaunchKernelGGL(k_final, dim3(32, 8, 2), dim3(256), 0, stream, ysb, cc, lq1, lk1, lq2, lk2, out);
}